// Round 1
// baseline (392.095 us; speedup 1.0000x reference)
//
#include <hip/hip_runtime.h>
#include <stdint.h>

// ---------------------------------------------------------------------------
// EfficientDet post-process: decode boxes, per-anchor max class score,
// exact stable top-k (k=1000), score threshold, greedy sequential NMS.
//
// Pipeline (all on `stream`, fixed kernel sequence for graph capture):
//   k_init      : zero control state / histograms / candidate buffer
//   k_score     : per-anchor max over 80 class scores -> sortable uint32 key
//   4x (k_hist + k_scan): MSB radix-select of the 1000th-largest key T
//   k_gather    : append all anchors with key >= T (atomic, unordered)
//   k_sort      : bitonic sort 2048 composite keys (score desc, idx asc),
//                 emit top-1000 candidate indices + scores in exact
//                 jax.lax.top_k order (stable ties -> lower index first)
//   k_decode    : decode+clip boxes, area, argmax class, valid flag
//   k_supmat    : 1000x1000 IoU>0.5 bitmatrix (16 uint64 words per row)
//   k_resolve   : chunked-wave sequential NMS resolution + write outputs
// ---------------------------------------------------------------------------

#define NK 1000
#define CAP 2048
#define NCLS 80
#define NW 16  // ceil(1024/64) words of keep bitmask

struct Ctrl {
  unsigned k_rem;
  unsigned prefix;
  unsigned cand_count;
  unsigned pad;
};

// Order-preserving float -> uint transform (total order matches float <).
static inline __device__ unsigned fkey(float f) {
  unsigned u = __float_as_uint(f);
  return (u & 0x80000000u) ? ~u : (u | 0x80000000u);
}
static inline __device__ float fkey_inv(unsigned k) {
  unsigned u = (k & 0x80000000u) ? (k & 0x7fffffffu) : ~k;
  return __uint_as_float(u);
}

__global__ void k_init(unsigned* __restrict__ hist, Ctrl* __restrict__ ctrl,
                       unsigned long long* __restrict__ cand_keys) {
  int t = blockIdx.x * blockDim.x + threadIdx.x;
  if (t < 4 * 256) hist[t] = 0u;
  if (t < CAP) cand_keys[t] = 0ull;
  if (t == 0) {
    ctrl->k_rem = NK;
    ctrl->prefix = 0u;
    ctrl->cand_count = 0u;
  }
}

// Per-anchor max over 80 class scores. cla row is 320 B, 16B-aligned.
__global__ void k_score(const float* __restrict__ cla, unsigned* __restrict__ keys, int A) {
  int a = blockIdx.x * blockDim.x + threadIdx.x;
  if (a >= A) return;
  const float4* p = (const float4*)(cla + (size_t)a * NCLS);
  float m = -3.402823466e38f;
#pragma unroll
  for (int j = 0; j < NCLS / 4; ++j) {
    float4 v = p[j];
    m = fmaxf(m, fmaxf(fmaxf(v.x, v.y), fmaxf(v.z, v.w)));
  }
  keys[a] = fkey(m);
}

// Radix-select histogram, pass p in {0,1,2,3}: 8-bit digit, MSB first.
__global__ void k_hist(const unsigned* __restrict__ keys, unsigned* __restrict__ hist_p,
                       const Ctrl* __restrict__ ctrl, int A, int p) {
  __shared__ unsigned lh[256];
  int t = threadIdx.x;
  lh[t] = 0u;
  __syncthreads();
  unsigned prefix = ctrl->prefix;
  int stride = gridDim.x * blockDim.x;
  for (int a = blockIdx.x * blockDim.x + t; a < A; a += stride) {
    unsigned k = keys[a];
    bool ok = (p == 0) || ((k >> (32 - 8 * p)) == prefix);
    if (ok) atomicAdd(&lh[(k >> (24 - 8 * p)) & 0xFFu], 1u);
  }
  __syncthreads();
  if (lh[t]) atomicAdd(&hist_p[t], lh[t]);
}

// Scan 256 bins high->low, pick the digit containing the k-th largest.
__global__ void k_scan(const unsigned* __restrict__ hist_p, Ctrl* __restrict__ ctrl) {
  if (threadIdx.x != 0 || blockIdx.x != 0) return;
  unsigned k = ctrl->k_rem;
  unsigned cum = 0u;
  int sel = 0;
  for (int d = 255; d >= 0; --d) {
    unsigned c = hist_p[d];
    if (cum + c >= k) { sel = d; break; }
    cum += c;
  }
  ctrl->prefix = (ctrl->prefix << 8) | (unsigned)sel;
  ctrl->k_rem = k - cum;
}

// Append every anchor with key >= T (T = ctrl->prefix after 4 passes).
// count(>T) = 1000 - k_rem, so sorting all >=T and taking the first 1000
// reproduces stable top-k exactly.
__global__ void k_gather(const unsigned* __restrict__ keys, Ctrl* __restrict__ ctrl,
                         unsigned long long* __restrict__ cand_keys, int A) {
  unsigned T = ctrl->prefix;
  int a = blockIdx.x * blockDim.x + threadIdx.x;
  if (a >= A) return;
  unsigned k = keys[a];
  if (k >= T) {
    unsigned pos = atomicAdd(&ctrl->cand_count, 1u);
    if (pos < CAP) {
      // composite key: (score desc, index asc) when sorted descending
      cand_keys[pos] = ((unsigned long long)k << 32) | (unsigned long long)(~(unsigned)a);
    }
  }
}

// Single-block bitonic sort of CAP=2048 64-bit keys, descending.
__global__ __launch_bounds__(1024) void k_sort(const unsigned long long* __restrict__ cand_keys,
                                               int* __restrict__ cand_idx,
                                               float* __restrict__ cand_score) {
  __shared__ unsigned long long s[CAP];
  int t = threadIdx.x;
  for (int i = t; i < CAP; i += 1024) s[i] = cand_keys[i];
  __syncthreads();
  for (int k = 2; k <= CAP; k <<= 1) {
    for (int j = k >> 1; j > 0; j >>= 1) {
      for (int i = t; i < CAP; i += 1024) {
        int ixj = i ^ j;
        if (ixj > i) {
          unsigned long long a = s[i], b = s[ixj];
          bool up = ((i & k) == 0);  // descending overall
          bool sw = up ? (a < b) : (a > b);
          if (sw) { s[i] = b; s[ixj] = a; }
        }
      }
      __syncthreads();
    }
  }
  for (int i = t; i < NK; i += 1024) {
    unsigned long long v = s[i];
    cand_idx[i] = (int)(~(unsigned)v);
    cand_score[i] = fkey_inv((unsigned)(v >> 32));
  }
}

// Decode + clip boxes, area, argmax class (first-max), valid flag.
__global__ void k_decode(const float* __restrict__ cla, const float* __restrict__ reg,
                         const float* __restrict__ anchors, const int* __restrict__ hp,
                         const int* __restrict__ wp, const int* __restrict__ cand_idx,
                         const float* __restrict__ cand_score, float4* __restrict__ cand_box,
                         float* __restrict__ cand_area, int* __restrict__ cand_cls,
                         int* __restrict__ cand_valid) {
  int i = blockIdx.x * blockDim.x + threadIdx.x;
  if (i >= NK) return;
  int a = cand_idx[i];
  float4 d = ((const float4*)reg)[a];
  float4 an = ((const float4*)anchors)[a];
  float W1 = (float)wp[0] - 1.0f;
  float H1 = (float)hp[0] - 1.0f;
  float wa = an.z - an.x, ha = an.w - an.y;
  float cxa = an.x + 0.5f * wa, cya = an.y + 0.5f * ha;
  float cx = cxa + d.x * wa, cy = cya + d.y * ha;
  float w = wa * expf(d.z), h = ha * expf(d.w);
  float x1 = cx - 0.5f * w, y1 = cy - 0.5f * h;
  float x2 = cx + 0.5f * w, y2 = cy + 0.5f * h;
  x1 = fminf(fmaxf(x1, 0.0f), W1);
  y1 = fminf(fmaxf(y1, 0.0f), H1);
  x2 = fminf(fmaxf(x2, 0.0f), W1);
  y2 = fminf(fmaxf(y2, 0.0f), H1);
  cand_box[i] = make_float4(x1, y1, x2, y2);
  cand_area[i] = fmaxf(x2 - x1, 0.0f) * fmaxf(y2 - y1, 0.0f);
  // argmax class, first occurrence of max (strict >)
  const float* row = cla + (size_t)a * NCLS;
  float m = -3.402823466e38f;
  int ci = 0;
  for (int j = 0; j < NCLS; ++j) {
    float v = row[j];
    if (v > m) { m = v; ci = j; }
  }
  cand_cls[i] = ci;
  cand_valid[i] = (cand_score[i] > 0.5f) ? 1 : 0;
}

// Suppression bitmatrix: sup[i][w] bit b <=> iou(box i, box w*64+b) > 0.5.
__global__ void k_supmat(const float4* __restrict__ cand_box, const float* __restrict__ cand_area,
                         unsigned long long* __restrict__ sup) {
  __shared__ float4 bx[NK];
  __shared__ float ar[NK];
  int t = threadIdx.x;
  for (int i = t; i < NK; i += blockDim.x) {
    bx[i] = cand_box[i];
    ar[i] = cand_area[i];
  }
  __syncthreads();
  int g = blockIdx.x * blockDim.x + t;
  int i = g >> 4;
  int w = g & 15;
  if (i >= NK) return;
  float4 bi = bx[i];
  float ai = ar[i];
  unsigned long long bits = 0ull;
  int j0 = w * 64;
  for (int b = 0; b < 64; ++b) {
    int j = j0 + b;
    if (j >= NK) break;
    float4 bj = bx[j];
    float xx1 = fmaxf(bi.x, bj.x), yy1 = fmaxf(bi.y, bj.y);
    float xx2 = fminf(bi.z, bj.z), yy2 = fminf(bi.w, bj.w);
    float inter = fmaxf(xx2 - xx1, 0.0f) * fmaxf(yy2 - yy1, 0.0f);
    float uni = ai + ar[j] - inter;
    float iou = inter / fmaxf(uni, 1e-8f);
    if (iou > 0.5f) bits |= (1ull << b);
  }
  sup[i * NW + w] = bits;
}

// Sequential NMS resolution (16 chunks of 64, wave 0 only) + output write.
__global__ __launch_bounds__(1024) void k_resolve(const unsigned long long* __restrict__ sup,
                                                  const int* __restrict__ cand_valid,
                                                  const float* __restrict__ cand_score,
                                                  const int* __restrict__ cand_cls,
                                                  const float4* __restrict__ cand_box,
                                                  float* __restrict__ out) {
  __shared__ unsigned long long keep_sh[NW];
  int t = threadIdx.x;
  if (t < 64) {
    int lane = t;
    unsigned long long keepw[NW];
#pragma unroll
    for (int c = 0; c < NW; ++c) {
      int row = c * 64 + lane;
      unsigned long long rw[NW];
      int v = 0;
      if (row < NK) {
#pragma unroll
        for (int w = 0; w < NW; ++w) rw[w] = sup[row * NW + w];
        v = cand_valid[row];
      } else {
#pragma unroll
        for (int w = 0; w < NW; ++w) rw[w] = 0ull;
      }
      // suppression by already-resolved earlier chunks
      unsigned long long prev = 0ull;
#pragma unroll
      for (int w = 0; w < NW; ++w) {
        if (w < c) prev |= rw[w] & keepw[w];
      }
      int flags = (v ? 2 : 0) | ((prev != 0ull) ? 1 : 0);
      unsigned Llo = (unsigned)rw[c];
      unsigned Lhi = (unsigned)(rw[c] >> 32);
      // in-chunk sequential resolution, identical in all lanes
      unsigned long long kept = 0ull;
      for (int b = 0; b < 64; ++b) {
        int fb = __shfl(flags, b, 64);
        unsigned lo = (unsigned)__shfl((int)Llo, b, 64);
        unsigned hi = (unsigned)__shfl((int)Lhi, b, 64);
        unsigned long long Lb = ((unsigned long long)hi << 32) | (unsigned long long)lo;
        bool kp = ((fb & 2) != 0) && ((fb & 1) == 0) && ((Lb & kept) == 0ull);
        kept |= ((unsigned long long)(kp ? 1u : 0u)) << b;
      }
      keepw[c] = kept;
    }
    if (lane == 0) {
#pragma unroll
      for (int w = 0; w < NW; ++w) keep_sh[w] = keepw[w];
    }
  }
  __syncthreads();
  for (int i = t; i < NK; i += 1024) {
    bool k = (keep_sh[i >> 6] >> (i & 63)) & 1ull;
    out[i] = k ? cand_score[i] : 0.0f;
    out[NK + i] = k ? (float)cand_cls[i] : -1.0f;  // int32 output written as float
    float4 b = cand_box[i];
    float4 ob = k ? b : make_float4(0.0f, 0.0f, 0.0f, 0.0f);
    ((float4*)(out + 2 * NK))[i] = ob;
  }
}

extern "C" void kernel_launch(void* const* d_in, const int* in_sizes, int n_in,
                              void* d_out, int out_size, void* d_ws, size_t ws_size,
                              hipStream_t stream) {
  const float* cla = (const float*)d_in[0];
  const float* reg = (const float*)d_in[1];
  const float* anchors = (const float*)d_in[2];
  const int* hp = (const int*)d_in[3];
  const int* wp = (const int*)d_in[4];
  float* out = (float*)d_out;
  int A = in_sizes[2] / 4;  // 441936

  // workspace carve-up (256B-aligned)
  char* ws = (char*)d_ws;
  size_t off = 0;
  auto carve = [&](size_t bytes) -> void* {
    void* p = ws + off;
    off += bytes;
    off = (off + 255) & ~(size_t)255;
    return p;
  };
  unsigned* keys = (unsigned*)carve((size_t)A * 4);
  unsigned* hist = (unsigned*)carve(4 * 256 * 4);
  Ctrl* ctrl = (Ctrl*)carve(sizeof(Ctrl));
  unsigned long long* cand_keys = (unsigned long long*)carve(CAP * 8);
  int* cand_idx = (int*)carve(1024 * 4);
  float* cand_score = (float*)carve(1024 * 4);
  float4* cand_box = (float4*)carve(1024 * 16);
  float* cand_area = (float*)carve(1024 * 4);
  int* cand_cls = (int*)carve(1024 * 4);
  int* cand_valid = (int*)carve(1024 * 4);
  unsigned long long* sup = (unsigned long long*)carve(1024 * NW * 8);
  (void)ws_size;
  (void)n_in;
  (void)out_size;

  int ablocks = (A + 255) / 256;

  k_init<<<8, 256, 0, stream>>>(hist, ctrl, cand_keys);
  k_score<<<ablocks, 256, 0, stream>>>(cla, keys, A);
  for (int p = 0; p < 4; ++p) {
    k_hist<<<512, 256, 0, stream>>>(keys, hist + p * 256, ctrl, A, p);
    k_scan<<<1, 64, 0, stream>>>(hist + p * 256, ctrl);
  }
  k_gather<<<ablocks, 256, 0, stream>>>(keys, ctrl, cand_keys, A);
  k_sort<<<1, 1024, 0, stream>>>(cand_keys, cand_idx, cand_score);
  k_decode<<<4, 256, 0, stream>>>(cla, reg, anchors, hp, wp, cand_idx, cand_score, cand_box,
                                  cand_area, cand_cls, cand_valid);
  k_supmat<<<63, 256, 0, stream>>>(cand_box, cand_area, sup);
  k_resolve<<<1, 1024, 0, stream>>>(sup, cand_valid, cand_score, cand_cls, cand_box, out);
}